// Round 14
// baseline (213.150 us; speedup 1.0000x reference)
//
#include <hip/hip_runtime.h>
#include <hip/hip_bf16.h>

// HierarchicalAttention: B=4,T=50,D=512, SRC=400, SENTS=16, WORDS=40.
// ATTRIBUTION ROUND: R13's 3-kernel pipeline with every kernel launched TWICE
// (all three are idempotent — bit-identical output). Clean total = base + S,
// S = kA + k2 + k3ac (+3 boundaries): separates kernel time from fixed cost.
//   kA   projections via bf16 MFMA with INLINE weight transpose (624 blocks)
//   k2   tanh scores — R7's 5280-block wave-fifth split (proven)
//   k3ac FUSED softmax + f32 context GEMV v2 (800 blocks, 8-deep row prefetch)

#define B_    4
#define T_    50
#define D_    512
#define SRC_  400
#define SENTS_ 16
#define WORDS_ 40
#define NW_   640      // SENTS*WORDS
#define NMEM_ 1040     // SRC + NW
#define NJOB_ 1056     // NMEM + SENTS (score jobs per batch)

#define C2L2E 2.8853900817779268f   // 2*log2(e): x -> exp2(C2L2E*x) = exp(2x)

typedef unsigned short ushort_t;
using s8v = __attribute__((ext_vector_type(8))) short;   // 8 bf16 (4 VGPRs)
using f4v = __attribute__((ext_vector_type(4))) float;   // MFMA accumulator

// ---- workspace layout ----
// f32 region (float offsets):
#define OFF_WQ_WORD 0
#define OFF_WQ_SENT 102400
#define OFF_WQ_PASS 204800
#define OFF_UH_SRC  307200
#define OFF_UH_WORD 1126400
#define OFF_UH_SENT 2437120
#define OFF_SC_SRC  2469888
#define OFF_SC_WORD 2549888
#define OFF_SC_SENT 2677888

__device__ __forceinline__ ushort_t f2b(float f) {
    __hip_bfloat16 h = __float2bfloat16(f);   // RNE
    return *(ushort_t*)&h;
}

// ---------------- kA: projections with inline weight transpose ----------------
__global__ __launch_bounds__(256) void kA(
    const float* __restrict__ source, const float* __restrict__ src_bank,
    const float* __restrict__ qa_sent_bank, const float* __restrict__ qa_word_bank,
    const float* __restrict__ w0, const float* __restrict__ w1,
    const float* __restrict__ w2, const float* __restrict__ w3,
    const float* __restrict__ w4, const float* __restrict__ w5,
    const float* __restrict__ bq_word, const float* __restrict__ bq_sent,
    const float* __restrict__ bq_pass,
    float* __restrict__ wsf)
{
    __shared__ float smemf[4224];   // At[0,1024) Bt[1024,2048) Wtmp[2048,4224)
    int bid = blockIdx.x;
    int tid = threadIdx.x;

    int z, rem;
    if (bid < 96)       { z = bid >> 5; rem = bid & 31; }
    else if (bid < 416) { z = 3; rem = bid - 96; }
    else if (bid < 616) { z = 4; rem = bid - 416; }
    else                { z = 5; rem = bid - 616; }
    int by = rem >> 3, bx = rem & 7;
    int M, atype; const float* bias; const float* W; float* C;
    switch (z) {
        case 0: M = 200;  atype = 0; bias = bq_word; W = w0; C = wsf + OFF_WQ_WORD; break;
        case 1: M = 200;  atype = 0; bias = bq_sent; W = w1; C = wsf + OFF_WQ_SENT; break;
        case 2: M = 200;  atype = 0; bias = bq_pass; W = w2; C = wsf + OFF_WQ_PASS; break;
        case 3: M = 2560; atype = 1; bias = nullptr; W = w3; C = wsf + OFF_UH_WORD; break;
        case 4: M = 1600; atype = 2; bias = nullptr; W = w4; C = wsf + OFF_UH_SRC;  break;
        default: M = 64;  atype = 3; bias = nullptr; W = w5; C = wsf + OFF_UH_SENT; break;
    }
    int m0 = by * 64, n0 = bx * 64;

    int lane = tid & 63, wvx = tid >> 6, quad = lane >> 4, l16 = lane & 15;
    int sm = tid >> 2, koff = (tid & 3) * 8;            // A staging: row, 8-chunk
    int rW = tid >> 3, cW = (tid & 7) * 8;              // W staging: k-row, 8 n-cols
    int rWs = rW * 68 + (cW ^ (((rW >> 3) & 3) << 4));  // swizzled Wtmp write base
    int nB = tid >> 2, kB8 = (tid & 3) * 8;             // Bt builder: n-row, 8 k
    int colp = nB ^ (((kB8 >> 3) & 3) << 4);            // swizzled Wtmp read col

    short* At = (short*)smemf;
    short* Bt = (short*)(smemf + 1024);
    float* Wtmp = smemf + 2048;                         // [32][68] f32, col-swizzled

    const float* arow = nullptr;
    {
        int rr = m0 + sm;
        if (rr < M) {
            if (atype == 0) arow = source + rr * D_;
            else if (atype == 1) { int b = rr / NW_; int j = rr - b * NW_;
                                   int se = j / WORDS_; int wd = j - se * WORDS_;
                                   arow = qa_word_bank + ((wd * B_ + b) * SENTS_ + se) * D_; }
            else if (atype == 2) { int b = rr / SRC_; int j = rr - b * SRC_;
                                   arow = src_bank + (j * B_ + b) * D_; }
            else                 { int b = rr >> 4; int s2 = rr & 15;
                                   arow = qa_sent_bank + (s2 * B_ + b) * D_; }
        }
    }
    const float* wbase = W + n0 + cW;

    auto loadA = [&](float* r, int kk) {
        if (arow) {
            float4 f0 = *(const float4*)(arow + kk * 32 + koff);
            float4 f1 = *(const float4*)(arow + kk * 32 + koff + 4);
            r[0]=f0.x; r[1]=f0.y; r[2]=f0.z; r[3]=f0.w;
            r[4]=f1.x; r[5]=f1.y; r[6]=f1.z; r[7]=f1.w;
        } else {
#pragma unroll
            for (int i = 0; i < 8; ++i) r[i] = 0.f;
        }
    };
    auto loadW = [&](float* r, int kk) {
        const float* p = wbase + (kk * 32 + rW) * D_;
        float4 f0 = *(const float4*)p;
        float4 f1 = *(const float4*)(p + 4);
        r[0]=f0.x; r[1]=f0.y; r[2]=f0.z; r[3]=f0.w;
        r[4]=f1.x; r[5]=f1.y; r[6]=f1.z; r[7]=f1.w;
    };
    auto storeWtmp = [&](const float* r) {
        *(float4*)(Wtmp + rWs)     = float4{r[0], r[1], r[2], r[3]};
        *(float4*)(Wtmp + rWs + 4) = float4{r[4], r[5], r[6], r[7]};
    };
    auto storeAt = [&](const float* r) {
        union { ushort_t u[8]; int4 v; } pk;
#pragma unroll
        for (int i = 0; i < 8; ++i) pk.u[i] = f2b(r[i]);
        *(int4*)(At + sm * 32 + koff) = pk.v;
    };
    auto buildBt = [&]() {
        union { ushort_t u[8]; int4 v; } pk;
#pragma unroll
        for (int i = 0; i < 8; ++i) pk.u[i] = f2b(Wtmp[(kB8 + i) * 68 + colp]);
        *(int4*)(Bt + nB * 32 + kB8) = pk.v;
    };

    f4v acc[4] = { {0.f,0.f,0.f,0.f}, {0.f,0.f,0.f,0.f},
                   {0.f,0.f,0.f,0.f}, {0.f,0.f,0.f,0.f} };

    float ac[8], an[8], wn[8];
    loadA(ac, 0);
    {
        float w0r[8];
        loadW(w0r, 0);
        storeWtmp(w0r);
    }
    loadW(wn, 1);
    loadA(an, 1);
    __syncthreads();

    for (int kk = 0; kk < 16; ++kk) {
        storeAt(ac);
        buildBt();
        __syncthreads();
        if (kk < 15) storeWtmp(wn);
        if (kk < 14) loadW(wn, kk + 2);
        if (kk < 15) {
#pragma unroll
            for (int i = 0; i < 8; ++i) ac[i] = an[i];
        }
        if (kk < 14) loadA(an, kk + 2);
        s8v af = *(const s8v*)(At + (wvx * 16 + l16) * 32 + quad * 8);
#pragma unroll
        for (int ng = 0; ng < 4; ++ng) {
            s8v bf = *(const s8v*)(Bt + (ng * 16 + l16) * 32 + quad * 8);
            acc[ng] = __builtin_amdgcn_mfma_f32_16x16x32_bf16(af, bf, acc[ng], 0, 0, 0);
        }
        __syncthreads();
    }

#pragma unroll
    for (int ng = 0; ng < 4; ++ng) {
        int col = n0 + ng * 16 + l16;
        float bb = bias ? bias[col] : 0.f;
#pragma unroll
        for (int rr2 = 0; rr2 < 4; ++rr2) {
            int row = m0 + wvx * 16 + quad * 4 + rr2;
            if (row < M) C[row * D_ + col] = (acc[ng][rr2] + bb) * C2L2E;
        }
    }
}

// ---------------- k2: additive-attention scores — 5 wave-fifths per job ----------------
__global__ __launch_bounds__(256) void k2_scores(
    const float* __restrict__ v_word, const float* __restrict__ v_sent,
    const float* __restrict__ v_pass,
    const int* __restrict__ src_lengths, const int* __restrict__ qa_word_lengths,
    float* __restrict__ wsf)
{
    int lane = threadIdx.x & 63;
    int jid = blockIdx.x * 4 + (threadIdx.x >> 6);   // 21120 wave-fifths, exact
    int job = jid / 5, fifth = jid - job * 5;
    int b = job / NJOB_, slot = job - b * NJOB_;
    const float* uh; const float* v; const float* wq; float* out; int ostride;
    if (slot < SRC_) {
        if (slot >= src_lengths[b]) return;           // masked: value never read
        uh = wsf + OFF_UH_SRC + (size_t)(b * SRC_ + slot) * D_;
        v = v_pass; wq = wsf + OFF_WQ_PASS + b * T_ * D_;
        out = wsf + OFF_SC_SRC + b * T_ * SRC_ + slot; ostride = SRC_;
    } else if (slot < NMEM_) {
        int j = slot - SRC_;
        int se = j / WORDS_; int wd = j - se * WORDS_;
        if (wd >= qa_word_lengths[b * SENTS_ + se]) return;  // masked
        uh = wsf + OFF_UH_WORD + (size_t)(b * NW_ + j) * D_;
        v = v_word; wq = wsf + OFF_WQ_WORD + b * T_ * D_;
        out = wsf + OFF_SC_WORD + b * T_ * NW_ + j; ostride = NW_;
    } else {
        int s2 = slot - NMEM_;
        uh = wsf + OFF_UH_SENT + (size_t)(b * SENTS_ + s2) * D_;
        v = v_sent; wq = wsf + OFF_WQ_SENT + b * T_ * D_;
        out = wsf + OFF_SC_SENT + b * T_ * SENTS_ + s2; ostride = SENTS_;
    }
    int d0 = lane * 8;
    float4 u0 = *(const float4*)(uh + d0);
    float4 u1 = *(const float4*)(uh + d0 + 4);
    float uhr[8] = {u0.x, u0.y, u0.z, u0.w, u1.x, u1.y, u1.z, u1.w};
    float4 v0 = *(const float4*)(v + d0);
    float4 v1 = *(const float4*)(v + d0 + 4);
    float vr[8] = {v0.x, v0.y, v0.z, v0.w, v1.x, v1.y, v1.z, v1.w};

    // Vsum = sum_d v[d] (broadcast to all lanes)
    float vs = ((vr[0] + vr[1]) + (vr[2] + vr[3])) + ((vr[4] + vr[5]) + (vr[6] + vr[7]));
#pragma unroll
    for (int off = 32; off > 0; off >>= 1) vs += __shfl_xor(vs, off, 64);

    const float* wqh = wq + (fifth * 10) * D_ + d0;
    int tbase = fifth * 10;
#pragma unroll 1
    for (int g = 0; g < 2; ++g) {
        float a5[5];
#pragma unroll
        for (int u5 = 0; u5 < 5; ++u5) {
            const float* wr = wqh + (g * 5 + u5) * D_;
            float4 w0 = *(const float4*)(wr);
            float4 w1 = *(const float4*)(wr + 4);
            float wrr[8] = {w0.x, w0.y, w0.z, w0.w, w1.x, w1.y, w1.z, w1.w};
            float a = 0.f;
#pragma unroll
            for (int j = 0; j < 8; ++j) {
                float e = __builtin_amdgcn_exp2f(wrr[j] + uhr[j]);  // exp(2x)
                float r = __builtin_amdgcn_rcpf(e + 1.f);           // sigmoid(-2x)
                a = fmaf(vr[j], r, a);
            }
            a5[u5] = a;
        }
#pragma unroll
        for (int off = 32; off > 0; off >>= 1) {
#pragma unroll
            for (int u5 = 0; u5 < 5; ++u5) a5[u5] += __shfl_xor(a5[u5], off, 64);
        }
        if (lane == 0) {
#pragma unroll
            for (int u5 = 0; u5 < 5; ++u5)
                out[(tbase + g * 5 + u5) * ostride] = fmaf(-2.f, a5[u5], vs);
        }
    }
}

// ---------------- k3ac v2: fused softmax + f32 context GEMV (800 blocks) ----------------
__global__ __launch_bounds__(256) void k3ac(
    const int* __restrict__ src_lengths, const int* __restrict__ qa_word_lengths,
    const float* __restrict__ wsf,
    const float* __restrict__ src_bank, const float* __restrict__ qa_word_bank,
    float* __restrict__ out)
{
    __shared__ float p[NMEM_];
    __shared__ float part[256];
    __shared__ float red[4];
    int tid = threadIdx.x, lane = tid & 63, wv = tid >> 6;
    int bid = blockIdx.x;
    int bt = bid >> 2, dq = bid & 3;
    int b = bt / T_, t = bt - b * T_;
    const float* sc_src  = wsf + OFF_SC_SRC  + bt * SRC_;
    const float* sc_word = wsf + OFF_SC_WORD + bt * NW_;
    const float* sc_sent = wsf + OFF_SC_SENT + bt * SENTS_;
    int slen = src_lengths[b];

    // ---- phase 1: combine + mask + softmax ----
    float mx = -3.0e38f;
    for (int j = tid; j < NMEM_; j += 256) {
        float val;
        if (j < SRC_) {
            val = (j < slen) ? sc_src[j] : -1e30f;
        } else {
            int jj = j - SRC_; int se = jj / WORDS_; int wd = jj - se * WORDS_;
            float raw = sc_word[jj] * sc_sent[se];
            val = (wd < qa_word_lengths[b * SENTS_ + se]) ? raw : -1e30f;
        }
        p[j] = val;
        mx = fmaxf(mx, val);
    }
#pragma unroll
    for (int off = 32; off > 0; off >>= 1) mx = fmaxf(mx, __shfl_xor(mx, off, 64));
    if (lane == 0) red[wv] = mx;
    __syncthreads();
    mx = fmaxf(fmaxf(red[0], red[1]), fmaxf(red[2], red[3]));
    __syncthreads();
    float lsum = 0.f;
    for (int j = tid; j < NMEM_; j += 256) {
        float e = __expf(p[j] - mx);   // masked: exp underflows to exactly 0.0f
        p[j] = e; lsum += e;
    }
#pragma unroll
    for (int off = 32; off > 0; off >>= 1) lsum += __shfl_xor(lsum, off, 64);
    if (lane == 0) red[wv] = lsum;
    __syncthreads();
    float inv = 1.f / (red[0] + red[1] + red[2] + red[3]);
    for (int j = tid; j < NMEM_; j += 256) p[j] *= inv;
    __syncthreads();

    // ---- phase 2: GEMV slice, col c of this 128-col d-slice, s-half sh ----
    int c = tid & 127, sh = tid >> 7;
    int d = dq * 128 + c;
    float acc = 0.f;

    auto gemv8 = [&](const float* bank, int strd, const float* pseg, int r0, int r1) {
        if (r0 >= r1) return;
        const float* rp = bank + (size_t)r0 * strd;
        float m0 = rp[0], m1 = rp[strd], m2 = rp[2*strd], m3 = rp[3*strd];
        float m4 = rp[4*strd], m5 = rp[5*strd], m6 = rp[6*strd], m7 = rp[7*strd];
        float4 pa = *(const float4*)(pseg + r0);
        float4 pb = *(const float4*)(pseg + r0 + 4);
        for (int r = r0; r + 8 < r1; r += 8) {
            const float* np = bank + (size_t)(r + 8) * strd;
            float n0 = np[0], n1 = np[strd], n2 = np[2*strd], n3 = np[3*strd];
            float n4 = np[4*strd], n5 = np[5*strd], n6 = np[6*strd], n7 = np[7*strd];
            float4 qa = *(const float4*)(pseg + r + 8);
            float4 qb = *(const float4*)(pseg + r + 12);
            acc = fmaf(pa.x, m0, acc); acc = fmaf(pa.y, m1, acc);
            acc = fmaf(pa.z, m2, acc); acc = fmaf(pa.w, m3, acc);
            acc = fmaf(pb.x, m4, acc); acc = fmaf(pb.y, m5, acc);
            acc = fmaf(pb.z, m6, acc); acc = fmaf(pb.w, m7, acc);
            m0 = n0; m1 = n1; m2 = n2; m3 = n3;
            m4 = n4; m5 = n5; m6 = n6; m7 = n7;
            pa = qa; pb = qb;
        }
        acc = fmaf(pa.x, m0, acc); acc = fmaf(pa.y, m1, acc);
        acc = fmaf(pa.z, m2, acc); acc = fmaf(pa.w, m3, acc);
        acc = fmaf(pb.x, m4, acc); acc = fmaf(pb.y, m5, acc);
        acc = fmaf(pb.z, m6, acc); acc = fmaf(pb.w, m7, acc);
    };

    {
        int slen8 = (slen + 7) & ~7;              // p==0 beyond slen (bit-exact)
        const float* bank = src_bank + (size_t)b * D_ + d;
        int s0 = (sh == 0) ? 0 : 200;
        int s1 = (sh == 0) ? min(slen8, 200) : slen8;   // 200 = 8*25
        gemv8(bank, B_ * D_, p, s0, s1);
    }
#pragma unroll 1
    for (int se = sh * 8; se < sh * 8 + 8; ++se) {
        int lim = qa_word_lengths[b * SENTS_ + se];
        int lim8 = (lim + 7) & ~7;                // p==0 beyond lim (bit-exact)
        const float* bank = qa_word_bank + ((size_t)b * SENTS_ + se) * D_ + d;
        gemv8(bank, B_ * SENTS_ * D_, p + SRC_ + se * WORDS_, 0, lim8);
    }

    part[tid] = acc;
    __syncthreads();
    if (tid < 128)
        out[(size_t)(b * T_ + t) * D_ + dq * 128 + tid] = part[tid] + part[tid + 128];
}

extern "C" void kernel_launch(void* const* d_in, const int* in_sizes, int n_in,
                              void* d_out, int out_size, void* d_ws, size_t ws_size,
                              hipStream_t stream)
{
    (void)in_sizes; (void)n_in; (void)out_size; (void)ws_size;
    const float* source          = (const float*)d_in[0];
    const float* src_bank        = (const float*)d_in[1];
    const int*   src_lengths     = (const int*)d_in[2];
    const float* qa_sent_bank    = (const float*)d_in[3];
    /* d_in[4] qa_sent_lengths unused (matches reference) */
    const float* qa_word_bank    = (const float*)d_in[5];
    const int*   qa_word_lengths = (const int*)d_in[6];
    const float* Wq_word = (const float*)d_in[7];
    const float* bq_word = (const float*)d_in[8];
    const float* Uc_word = (const float*)d_in[9];
    const float* v_word  = (const float*)d_in[10];
    const float* Wq_sent = (const float*)d_in[11];
    const float* bq_sent = (const float*)d_in[12];
    const float* Uc_sent = (const float*)d_in[13];
    const float* v_sent  = (const float*)d_in[14];
    const float* Wq_pass = (const float*)d_in[15];
    const float* bq_pass = (const float*)d_in[16];
    const float* Uc_pass = (const float*)d_in[17];
    const float* v_pass  = (const float*)d_in[18];

    float* wsf = (float*)d_ws;
    float* out = (float*)d_out;

    // ATTRIBUTION: every kernel launched twice (idempotent — identical output).
    // Clean-run delta vs R13 = kA + k2 + k3ac (+3 boundaries).
    kA<<<dim3(624), dim3(256), 0, stream>>>(
        source, src_bank, qa_sent_bank, qa_word_bank,
        Wq_word, Wq_sent, Wq_pass, Uc_word, Uc_pass, Uc_sent,
        bq_word, bq_sent, bq_pass, wsf);
    kA<<<dim3(624), dim3(256), 0, stream>>>(
        source, src_bank, qa_sent_bank, qa_word_bank,
        Wq_word, Wq_sent, Wq_pass, Uc_word, Uc_pass, Uc_sent,
        bq_word, bq_sent, bq_pass, wsf);
    k2_scores<<<dim3(5280), dim3(256), 0, stream>>>(
        v_word, v_sent, v_pass, src_lengths, qa_word_lengths, wsf);
    k2_scores<<<dim3(5280), dim3(256), 0, stream>>>(
        v_word, v_sent, v_pass, src_lengths, qa_word_lengths, wsf);
    k3ac<<<dim3(800), dim3(256), 0, stream>>>(
        src_lengths, qa_word_lengths, wsf, src_bank, qa_word_bank, out);
    k3ac<<<dim3(800), dim3(256), 0, stream>>>(
        src_lengths, qa_word_lengths, wsf, src_bank, qa_word_bank, out);
}

// Round 15
// 159.813 us; speedup vs baseline: 1.3337x; 1.3337x over previous
//
#include <hip/hip_runtime.h>
#include <hip/hip_bf16.h>

// HierarchicalAttention: B=4,T=50,D=512, SRC=400, SENTS=16, WORDS=40.
// 3-launch pipeline. R14 attribution: kernels sum ~54us, fixed ~105us.
//   kA   projections via bf16 MFMA with INLINE weight transpose (624 blocks)
//   k2   tanh scores v3 — 2 slots per wave-fifth (10560 wave-jobs: keeps
//        ~5 waves/SIMD TLP while halving wq L2 traffic 214->107MB)
//   k3ac fused softmax + f32 context GEMV v3 — 512 thr, 4-way s-split
//        (6400 waves, quartered serial row chains), 8-row-group prefetch

#define B_    4
#define T_    50
#define D_    512
#define SRC_  400
#define SENTS_ 16
#define WORDS_ 40
#define NW_   640      // SENTS*WORDS
#define NMEM_ 1040     // SRC + NW

#define C2L2E 2.8853900817779268f   // 2*log2(e): x -> exp2(C2L2E*x) = exp(2x)

typedef unsigned short ushort_t;
using s8v = __attribute__((ext_vector_type(8))) short;   // 8 bf16 (4 VGPRs)
using f4v = __attribute__((ext_vector_type(4))) float;   // MFMA accumulator

// ---- workspace layout ----
// f32 region (float offsets):
#define OFF_WQ_WORD 0
#define OFF_WQ_SENT 102400
#define OFF_WQ_PASS 204800
#define OFF_UH_SRC  307200
#define OFF_UH_WORD 1126400
#define OFF_UH_SENT 2437120
#define OFF_SC_SRC  2469888
#define OFF_SC_WORD 2549888
#define OFF_SC_SENT 2677888

__device__ __forceinline__ ushort_t f2b(float f) {
    __hip_bfloat16 h = __float2bfloat16(f);   // RNE
    return *(ushort_t*)&h;
}

// ---------------- kA: projections with inline weight transpose ----------------
// 624 compact GEMM blocks (z0-2: 32 each M=200, z3: 320 M=2560, z4: 200 M=1600,
// z5: 8 M=64). Block tile 64x64, K=512 in 16 steps; 2 barriers/step; depth-2
// register prefetch. Same RNE conversion point as the original k0f+k1 path.
__global__ __launch_bounds__(256) void kA(
    const float* __restrict__ source, const float* __restrict__ src_bank,
    const float* __restrict__ qa_sent_bank, const float* __restrict__ qa_word_bank,
    const float* __restrict__ w0, const float* __restrict__ w1,
    const float* __restrict__ w2, const float* __restrict__ w3,
    const float* __restrict__ w4, const float* __restrict__ w5,
    const float* __restrict__ bq_word, const float* __restrict__ bq_sent,
    const float* __restrict__ bq_pass,
    float* __restrict__ wsf)
{
    __shared__ float smemf[4224];   // At[0,1024) Bt[1024,2048) Wtmp[2048,4224)
    int bid = blockIdx.x;
    int tid = threadIdx.x;

    int z, rem;
    if (bid < 96)       { z = bid >> 5; rem = bid & 31; }
    else if (bid < 416) { z = 3; rem = bid - 96; }
    else if (bid < 616) { z = 4; rem = bid - 416; }
    else                { z = 5; rem = bid - 616; }
    int by = rem >> 3, bx = rem & 7;
    int M, atype; const float* bias; const float* W; float* C;
    switch (z) {
        case 0: M = 200;  atype = 0; bias = bq_word; W = w0; C = wsf + OFF_WQ_WORD; break;
        case 1: M = 200;  atype = 0; bias = bq_sent; W = w1; C = wsf + OFF_WQ_SENT; break;
        case 2: M = 200;  atype = 0; bias = bq_pass; W = w2; C = wsf + OFF_WQ_PASS; break;
        case 3: M = 2560; atype = 1; bias = nullptr; W = w3; C = wsf + OFF_UH_WORD; break;
        case 4: M = 1600; atype = 2; bias = nullptr; W = w4; C = wsf + OFF_UH_SRC;  break;
        default: M = 64;  atype = 3; bias = nullptr; W = w5; C = wsf + OFF_UH_SENT; break;
    }
    int m0 = by * 64, n0 = bx * 64;

    int lane = tid & 63, wvx = tid >> 6, quad = lane >> 4, l16 = lane & 15;
    int sm = tid >> 2, koff = (tid & 3) * 8;            // A staging: row, 8-chunk
    int rW = tid >> 3, cW = (tid & 7) * 8;              // W staging: k-row, 8 n-cols
    int rWs = rW * 68 + (cW ^ (((rW >> 3) & 3) << 4));  // swizzled Wtmp write base
    int nB = tid >> 2, kB8 = (tid & 3) * 8;             // Bt builder: n-row, 8 k
    int colp = nB ^ (((kB8 >> 3) & 3) << 4);            // swizzled Wtmp read col

    short* At = (short*)smemf;
    short* Bt = (short*)(smemf + 1024);
    float* Wtmp = smemf + 2048;                         // [32][68] f32, col-swizzled

    const float* arow = nullptr;
    {
        int rr = m0 + sm;
        if (rr < M) {
            if (atype == 0) arow = source + rr * D_;
            else if (atype == 1) { int b = rr / NW_; int j = rr - b * NW_;
                                   int se = j / WORDS_; int wd = j - se * WORDS_;
                                   arow = qa_word_bank + ((wd * B_ + b) * SENTS_ + se) * D_; }
            else if (atype == 2) { int b = rr / SRC_; int j = rr - b * SRC_;
                                   arow = src_bank + (j * B_ + b) * D_; }
            else                 { int b = rr >> 4; int s2 = rr & 15;
                                   arow = qa_sent_bank + (s2 * B_ + b) * D_; }
        }
    }
    const float* wbase = W + n0 + cW;

    auto loadA = [&](float* r, int kk) {
        if (arow) {
            float4 f0 = *(const float4*)(arow + kk * 32 + koff);
            float4 f1 = *(const float4*)(arow + kk * 32 + koff + 4);
            r[0]=f0.x; r[1]=f0.y; r[2]=f0.z; r[3]=f0.w;
            r[4]=f1.x; r[5]=f1.y; r[6]=f1.z; r[7]=f1.w;
        } else {
#pragma unroll
            for (int i = 0; i < 8; ++i) r[i] = 0.f;
        }
    };
    auto loadW = [&](float* r, int kk) {
        const float* p = wbase + (kk * 32 + rW) * D_;
        float4 f0 = *(const float4*)p;
        float4 f1 = *(const float4*)(p + 4);
        r[0]=f0.x; r[1]=f0.y; r[2]=f0.z; r[3]=f0.w;
        r[4]=f1.x; r[5]=f1.y; r[6]=f1.z; r[7]=f1.w;
    };
    auto storeWtmp = [&](const float* r) {
        *(float4*)(Wtmp + rWs)     = float4{r[0], r[1], r[2], r[3]};
        *(float4*)(Wtmp + rWs + 4) = float4{r[4], r[5], r[6], r[7]};
    };
    auto storeAt = [&](const float* r) {
        union { ushort_t u[8]; int4 v; } pk;
#pragma unroll
        for (int i = 0; i < 8; ++i) pk.u[i] = f2b(r[i]);
        *(int4*)(At + sm * 32 + koff) = pk.v;
    };
    auto buildBt = [&]() {
        union { ushort_t u[8]; int4 v; } pk;
#pragma unroll
        for (int i = 0; i < 8; ++i) pk.u[i] = f2b(Wtmp[(kB8 + i) * 68 + colp]);
        *(int4*)(Bt + nB * 32 + kB8) = pk.v;
    };

    f4v acc[4] = { {0.f,0.f,0.f,0.f}, {0.f,0.f,0.f,0.f},
                   {0.f,0.f,0.f,0.f}, {0.f,0.f,0.f,0.f} };

    float ac[8], an[8], wn[8];
    loadA(ac, 0);
    {
        float w0r[8];
        loadW(w0r, 0);
        storeWtmp(w0r);
    }
    loadW(wn, 1);
    loadA(an, 1);
    __syncthreads();

    for (int kk = 0; kk < 16; ++kk) {
        storeAt(ac);
        buildBt();
        __syncthreads();
        if (kk < 15) storeWtmp(wn);
        if (kk < 14) loadW(wn, kk + 2);
        if (kk < 15) {
#pragma unroll
            for (int i = 0; i < 8; ++i) ac[i] = an[i];
        }
        if (kk < 14) loadA(an, kk + 2);
        s8v af = *(const s8v*)(At + (wvx * 16 + l16) * 32 + quad * 8);
#pragma unroll
        for (int ng = 0; ng < 4; ++ng) {
            s8v bf = *(const s8v*)(Bt + (ng * 16 + l16) * 32 + quad * 8);
            acc[ng] = __builtin_amdgcn_mfma_f32_16x16x32_bf16(af, bf, acc[ng], 0, 0, 0);
        }
        __syncthreads();
    }

#pragma unroll
    for (int ng = 0; ng < 4; ++ng) {
        int col = n0 + ng * 16 + l16;
        float bb = bias ? bias[col] : 0.f;
#pragma unroll
        for (int rr2 = 0; rr2 < 4; ++rr2) {
            int row = m0 + wvx * 16 + quad * 4 + rr2;
            if (row < M) C[row * D_ + col] = (acc[ng][rr2] + bb) * C2L2E;
        }
    }
}

// ---------------- k2 v3: scores — 2 slots per wave-fifth ----------------
// 2640 blocks x 4 waves = 10560 wave-jobs: (b, slot-PAIR, fifth). Each active
// wave holds 2 uh rows in registers and streams 10 wq rows, using each row for
// both slots (wq L2 traffic halved vs R7; active waves ~5360 ≈ 5/SIMD). Pairs
// never cross segment/sentence boundaries (400,40,16 all even); contiguous
// masks => pair-skip iff slot0 masked; per-slot guard at store. Per-slot fma
// chain identical to R7 -> score bits identical.
// score = Vsum - 2*sum_d v[d]*sigmoid(-2x); exp(2x)=exp2(pre-scaled sum).
__global__ __launch_bounds__(256) void k2_scores(
    const float* __restrict__ v_word, const float* __restrict__ v_sent,
    const float* __restrict__ v_pass,
    const int* __restrict__ src_lengths, const int* __restrict__ qa_word_lengths,
    float* __restrict__ wsf)
{
    int lane = threadIdx.x & 63;
    int jid = blockIdx.x * 4 + (threadIdx.x >> 6);   // 10560 wave-jobs, exact
    int job = jid / 5, fifth = jid - job * 5;
    int b = job / 528, pair = job - b * 528;         // 528 pairs per batch
    const float* uh; const float* v; const float* wq; float* out; int ostride;
    int nact;
    if (pair < 200) {
        int slot0 = pair * 2;
        int slen = src_lengths[b];
        if (slot0 >= slen) return;                    // whole pair masked
        nact = min(2, slen - slot0);
        uh = wsf + OFF_UH_SRC + (size_t)(b * SRC_ + slot0) * D_;
        v = v_pass; wq = wsf + OFF_WQ_PASS + b * T_ * D_;
        out = wsf + OFF_SC_SRC + b * T_ * SRC_ + slot0; ostride = SRC_;
    } else if (pair < 520) {
        int jw = (pair - 200) * 2;
        int se = jw / WORDS_; int wd = jw - se * WORDS_;
        int lim = qa_word_lengths[b * SENTS_ + se];
        if (wd >= lim) return;                        // whole pair masked
        nact = min(2, lim - wd);
        uh = wsf + OFF_UH_WORD + (size_t)(b * NW_ + jw) * D_;
        v = v_word; wq = wsf + OFF_WQ_WORD + b * T_ * D_;
        out = wsf + OFF_SC_WORD + b * T_ * NW_ + jw; ostride = NW_;
    } else {
        int s2 = (pair - 520) * 2;
        nact = 2;                                     // sentences unmasked
        uh = wsf + OFF_UH_SENT + (size_t)(b * SENTS_ + s2) * D_;
        v = v_sent; wq = wsf + OFF_WQ_SENT + b * T_ * D_;
        out = wsf + OFF_SC_SENT + b * T_ * SENTS_ + s2; ostride = SENTS_;
    }
    int d0 = lane * 8;
    float uhr[2][8];
#pragma unroll
    for (int u = 0; u < 2; ++u) {
        float4 f0 = *(const float4*)(uh + u * D_ + d0);
        float4 f1 = *(const float4*)(uh + u * D_ + d0 + 4);
        uhr[u][0]=f0.x; uhr[u][1]=f0.y; uhr[u][2]=f0.z; uhr[u][3]=f0.w;
        uhr[u][4]=f1.x; uhr[u][5]=f1.y; uhr[u][6]=f1.z; uhr[u][7]=f1.w;
    }
    float4 v0 = *(const float4*)(v + d0);
    float4 v1 = *(const float4*)(v + d0 + 4);
    float vr[8] = {v0.x, v0.y, v0.z, v0.w, v1.x, v1.y, v1.z, v1.w};

    // Vsum = sum_d v[d] (broadcast to all lanes)
    float vs = ((vr[0] + vr[1]) + (vr[2] + vr[3])) + ((vr[4] + vr[5]) + (vr[6] + vr[7]));
#pragma unroll
    for (int off = 32; off > 0; off >>= 1) vs += __shfl_xor(vs, off, 64);

    const float* wqh = wq + (fifth * 10) * D_ + d0;
    int tbase = fifth * 10;
#pragma unroll 1
    for (int g = 0; g < 2; ++g) {
        float a[2][5];   // [slot][t5] — all static indices under full unroll
#pragma unroll
        for (int u5 = 0; u5 < 5; ++u5) {
            const float* wr = wqh + (g * 5 + u5) * D_;
            float4 w0 = *(const float4*)(wr);
            float4 w1 = *(const float4*)(wr + 4);
            float wrr[8] = {w0.x, w0.y, w0.z, w0.w, w1.x, w1.y, w1.z, w1.w};
#pragma unroll
            for (int u = 0; u < 2; ++u) {
                float acc = 0.f;
#pragma unroll
                for (int j = 0; j < 8; ++j) {
                    float e = __builtin_amdgcn_exp2f(wrr[j] + uhr[u][j]);  // exp(2x)
                    float rc = __builtin_amdgcn_rcpf(e + 1.f);             // sigmoid(-2x)
                    acc = fmaf(vr[j], rc, acc);
                }
                a[u][u5] = acc;
            }
        }
        // 10 interleaved butterfly reductions (static indices -> registers)
#pragma unroll
        for (int off = 32; off > 0; off >>= 1) {
#pragma unroll
            for (int u = 0; u < 2; ++u)
#pragma unroll
                for (int u5 = 0; u5 < 5; ++u5)
                    a[u][u5] += __shfl_xor(a[u][u5], off, 64);
        }
        if (lane == 0) {
#pragma unroll
            for (int u5 = 0; u5 < 5; ++u5) {
                int trow = (tbase + g * 5 + u5) * ostride;
#pragma unroll
                for (int u = 0; u < 2; ++u)
                    if (u < nact) out[trow + u] = fmaf(-2.f, a[u][u5], vs);
            }
        }
    }
}

// ---------------- k3ac v3: fused softmax + f32 context GEMV ----------------
// 800 blocks x 512 thr. Block = (bt, dq): d-slice of 128 cols. Phase 1: full
// softmax into LDS p[1040] (4x redundant across d-slices — trivial). Phase 2:
// thread = (col c = tid&127, s-quarter sq = tid>>7); 8-row groups with depth-1
// group prefetch; src quarters 104-row aligned, word quarters = 4 sentences;
// lengths rounded to 8 (p exactly 0.0 in pad — bit-exact). 4-way LDS combine.
__global__ __launch_bounds__(512) void k3ac(
    const int* __restrict__ src_lengths, const int* __restrict__ qa_word_lengths,
    const float* __restrict__ wsf,
    const float* __restrict__ src_bank, const float* __restrict__ qa_word_bank,
    float* __restrict__ out)
{
    __shared__ float p[NMEM_];
    __shared__ float part[512];
    __shared__ float red[8];
    int tid = threadIdx.x, lane = tid & 63, wv = tid >> 6;   // 8 waves
    int bid = blockIdx.x;
    int bt = bid >> 2, dq = bid & 3;
    int b = bt / T_, t = bt - b * T_;
    const float* sc_src  = wsf + OFF_SC_SRC  + bt * SRC_;
    const float* sc_word = wsf + OFF_SC_WORD + bt * NW_;
    const float* sc_sent = wsf + OFF_SC_SENT + bt * SENTS_;
    int slen = src_lengths[b];

    // ---- phase 1: combine + mask + softmax ----
    float mx = -3.0e38f;
    for (int j = tid; j < NMEM_; j += 512) {
        float val;
        if (j < SRC_) {
            val = (j < slen) ? sc_src[j] : -1e30f;
        } else {
            int jj = j - SRC_; int se = jj / WORDS_; int wd = jj - se * WORDS_;
            float raw = sc_word[jj] * sc_sent[se];
            val = (wd < qa_word_lengths[b * SENTS_ + se]) ? raw : -1e30f;
        }
        p[j] = val;
        mx = fmaxf(mx, val);
    }
#pragma unroll
    for (int off = 32; off > 0; off >>= 1) mx = fmaxf(mx, __shfl_xor(mx, off, 64));
    if (lane == 0) red[wv] = mx;
    __syncthreads();
    mx = fmaxf(fmaxf(fmaxf(red[0], red[1]), fmaxf(red[2], red[3])),
               fmaxf(fmaxf(red[4], red[5]), fmaxf(red[6], red[7])));
    __syncthreads();
    float lsum = 0.f;
    for (int j = tid; j < NMEM_; j += 512) {
        float e = __expf(p[j] - mx);   // masked: exp underflows to exactly 0.0f
        p[j] = e; lsum += e;
    }
#pragma unroll
    for (int off = 32; off > 0; off >>= 1) lsum += __shfl_xor(lsum, off, 64);
    if (lane == 0) red[wv] = lsum;
    __syncthreads();
    float inv = 1.f / (((red[0] + red[1]) + (red[2] + red[3])) +
                       ((red[4] + red[5]) + (red[6] + red[7])));
    for (int j = tid; j < NMEM_; j += 512) p[j] *= inv;
    __syncthreads();

    // ---- phase 2: GEMV slice, col c of this 128-col d-slice, s-quarter sq ----
    int c = tid & 127, sq = tid >> 7;
    int d = dq * 128 + c;
    float acc = 0.f;

    auto gemv8 = [&](const float* bank, int strd, const float* pseg, int r0, int r1) {
        if (r0 >= r1) return;
        const float* rp = bank + (size_t)r0 * strd;
        float m0 = rp[0], m1 = rp[strd], m2 = rp[2*strd], m3 = rp[3*strd];
        float m4 = rp[4*strd], m5 = rp[5*strd], m6 = rp[6*strd], m7 = rp[7*strd];
        float4 pa = *(const float4*)(pseg + r0);
        float4 pb = *(const float4*)(pseg + r0 + 4);
        for (int r = r0; r + 8 < r1; r += 8) {
            const float* np = bank + (size_t)(r + 8) * strd;
            float n0 = np[0], n1 = np[strd], n2 = np[2*strd], n3 = np[3*strd];
            float n4 = np[4*strd], n5 = np[5*strd], n6 = np[6*strd], n7 = np[7*strd];
            float4 qa = *(const float4*)(pseg + r + 8);
            float4 qb = *(const float4*)(pseg + r + 12);
            acc = fmaf(pa.x, m0, acc); acc = fmaf(pa.y, m1, acc);
            acc = fmaf(pa.z, m2, acc); acc = fmaf(pa.w, m3, acc);
            acc = fmaf(pb.x, m4, acc); acc = fmaf(pb.y, m5, acc);
            acc = fmaf(pb.z, m6, acc); acc = fmaf(pb.w, m7, acc);
            m0 = n0; m1 = n1; m2 = n2; m3 = n3;
            m4 = n4; m5 = n5; m6 = n6; m7 = n7;
            pa = qa; pb = qb;
        }
        acc = fmaf(pa.x, m0, acc); acc = fmaf(pa.y, m1, acc);
        acc = fmaf(pa.z, m2, acc); acc = fmaf(pa.w, m3, acc);
        acc = fmaf(pb.x, m4, acc); acc = fmaf(pb.y, m5, acc);
        acc = fmaf(pb.z, m6, acc); acc = fmaf(pb.w, m7, acc);
    };

    // src segment: quarter sq covers rows [sq*104, min(slen8, sq*104+104))
    {
        int slen8 = (slen + 7) & ~7;              // p==0 beyond slen (bit-exact)
        const float* bank = src_bank + (size_t)b * D_ + d;
        int r0 = sq * 104;
        int r1 = min(slen8, r0 + 104);
        gemv8(bank, B_ * D_, p, r0, r1);
    }
    // word segment: quarter sq covers sentences [sq*4, sq*4+4)
#pragma unroll 1
    for (int se = sq * 4; se < sq * 4 + 4; ++se) {
        int lim = qa_word_lengths[b * SENTS_ + se];
        int lim8 = (lim + 7) & ~7;                // p==0 beyond lim (bit-exact)
        const float* bank = qa_word_bank + ((size_t)b * SENTS_ + se) * D_ + d;
        gemv8(bank, B_ * SENTS_ * D_, p + SRC_ + se * WORDS_, 0, lim8);
    }

    part[tid] = acc;
    __syncthreads();
    if (tid < 128)
        out[(size_t)(b * T_ + t) * D_ + dq * 128 + tid] =
            (part[tid] + part[tid + 128]) + (part[tid + 256] + part[tid + 384]);
}

extern "C" void kernel_launch(void* const* d_in, const int* in_sizes, int n_in,
                              void* d_out, int out_size, void* d_ws, size_t ws_size,
                              hipStream_t stream)
{
    (void)in_sizes; (void)n_in; (void)out_size; (void)ws_size;
    const float* source          = (const float*)d_in[0];
    const float* src_bank        = (const float*)d_in[1];
    const int*   src_lengths     = (const int*)d_in[2];
    const float* qa_sent_bank    = (const float*)d_in[3];
    /* d_in[4] qa_sent_lengths unused (matches reference) */
    const float* qa_word_bank    = (const float*)d_in[5];
    const int*   qa_word_lengths = (const int*)d_in[6];
    const float* Wq_word = (const float*)d_in[7];
    const float* bq_word = (const float*)d_in[8];
    const float* Uc_word = (const float*)d_in[9];
    const float* v_word  = (const float*)d_in[10];
    const float* Wq_sent = (const float*)d_in[11];
    const float* bq_sent = (const float*)d_in[12];
    const float* Uc_sent = (const float*)d_in[13];
    const float* v_sent  = (const float*)d_in[14];
    const float* Wq_pass = (const float*)d_in[15];
    const float* bq_pass = (const float*)d_in[16];
    const float* Uc_pass = (const float*)d_in[17];
    const float* v_pass  = (const float*)d_in[18];

    float* wsf = (float*)d_ws;
    float* out = (float*)d_out;

    // W order must match kA segment order:
    // 0:Wq_word 1:Wq_sent 2:Wq_pass 3:Uc_word 4:Uc_pass 5:Uc_sent
    kA<<<dim3(624), dim3(256), 0, stream>>>(
        source, src_bank, qa_sent_bank, qa_word_bank,
        Wq_word, Wq_sent, Wq_pass, Uc_word, Uc_pass, Uc_sent,
        bq_word, bq_sent, bq_pass, wsf);
    k2_scores<<<dim3(2640), dim3(256), 0, stream>>>(
        v_word, v_sent, v_pass, src_lengths, qa_word_lengths, wsf);
    k3ac<<<dim3(800), dim3(512), 0, stream>>>(
        src_lengths, qa_word_lengths, wsf, src_bank, qa_word_bank, out);
}

// Round 16
// 152.686 us; speedup vs baseline: 1.3960x; 1.0467x over previous
//
#include <hip/hip_runtime.h>
#include <hip/hip_bf16.h>

// HierarchicalAttention: B=4,T=50,D=512, SRC=400, SENTS=16, WORDS=40.
// FINAL LOCK-IN: session-best configuration (R7, measured 153.3us), byte-exact.
// 5-launch pipeline:
//   k0f  fused transposes: weights->bf16 Wt[n][k], banks->bf16 Mt[b][d][s]
//   k1   MFMA projections, depth-2 register prefetch (outputs pre-scaled by 2*log2e)
//   k2   tanh scores — 5 wave-fifths per (b,slot), 10 t-rows each (21120 waves)
//   k3a  hier combine + mask + softmax -> bf16 P
//   k3c  MFMA context GEMM, depth-3 register prefetch (P x M -> out)
// Session model (R14 attribution): fixed ~105us (fill+harness), kernels ~50us,
// all latency-bound at this problem size; 7 optimization attempts on the
// kernel sum were neutral. The MFMA tail (k3a+k3c) is ~6us faster than the
// fused f32 GEMV tail (R13/R15) — hence this configuration.

#define B_    4
#define T_    50
#define D_    512
#define SRC_  400
#define SENTS_ 16
#define WORDS_ 40
#define NW_   640      // SENTS*WORDS
#define NMEM_ 1040     // SRC + NW
#define NK_   1056     // NMEM padded to 32*33 for MFMA K-loop
#define NJOB_ 1056     // NMEM + SENTS (score jobs per batch)

#define C2L2E 2.8853900817779268f   // 2*log2(e): x -> exp2(C2L2E*x) = exp(2x)

typedef unsigned short ushort_t;
using s8v = __attribute__((ext_vector_type(8))) short;   // 8 bf16 (4 VGPRs)
using f4v = __attribute__((ext_vector_type(4))) float;   // MFMA accumulator

// ---- workspace layout ----
// f32 region (float offsets):
#define OFF_WQ_WORD 0
#define OFF_WQ_SENT 102400
#define OFF_WQ_PASS 204800
#define OFF_UH_SRC  307200
#define OFF_UH_WORD 1126400
#define OFF_UH_SENT 2437120
#define OFF_SC_SRC  2469888
#define OFF_SC_WORD 2549888
#define OFF_SC_SENT 2677888
// bf16 regions (byte offsets):
#define P_BYTE_OFF  10724352ull   // P[b][64][1056]  bf16 = 540672 B
#define MT_BYTE_OFF 11265024ull   // Mt[b][512][1056] bf16 = 4325376 B
#define WT_BYTE_OFF 15590400ull   // Wt[6][512][512] bf16 = 3145728 B

__device__ __forceinline__ ushort_t f2b(float f) {
    __hip_bfloat16 h = __float2bfloat16(f);   // RNE
    return *(ushort_t*)&h;
}

// ---------------- k0f: fused transposes (compact 1D grid, 3648 blocks) ----------------
// bid < 1536: weight W[k][n] -> Wt[n][k]  (z = bid>>8, 16x16 tiles)
// bid >= 1536: banks -> Mt[b][d][s]       (4 b x 16 d-tiles x 33 s-tiles)
__global__ __launch_bounds__(256) void k0f_transpose(
    const float* __restrict__ w0, const float* __restrict__ w1,
    const float* __restrict__ w2, const float* __restrict__ w3,
    const float* __restrict__ w4, const float* __restrict__ w5,
    const float* __restrict__ src_bank, const float* __restrict__ qa_word_bank,
    ushort_t* __restrict__ wt, ushort_t* __restrict__ mt)
{
    __shared__ float tile[32][33];
    int bid = blockIdx.x;
    int tx = threadIdx.x & 31, ty = threadIdx.x >> 5;
    if (bid < 1536) {
        int z = bid >> 8, r = bid & 255;
        int n0 = (r & 15) * 32, k0 = (r >> 4) * 32;
        const float* W;
        switch (z) {
            case 0: W = w0; break; case 1: W = w1; break; case 2: W = w2; break;
            case 3: W = w3; break; case 4: W = w4; break; default: W = w5; break;
        }
        ushort_t* Wt = wt + z * (D_ * D_);
#pragma unroll
        for (int a = 0; a < 4; ++a)
            tile[ty + a * 8][tx] = W[(k0 + ty + a * 8) * D_ + n0 + tx];
        __syncthreads();
#pragma unroll
        for (int a = 0; a < 4; ++a)
            Wt[(n0 + ty + a * 8) * D_ + k0 + tx] = f2b(tile[tx][ty + a * 8]);
    } else {
        int tb = bid - 1536;
        int b = tb / 528, r = tb - b * 528;
        int s0 = (r % 33) * 32, d0 = (r / 33) * 32;
#pragma unroll
        for (int a = 0; a < 4; ++a) {
            int s = s0 + ty + a * 8;
            float val = 0.f;
            if (s < SRC_) {
                val = src_bank[(s * B_ + b) * D_ + d0 + tx];
            } else if (s < NMEM_) {
                int j = s - SRC_; int se = j / WORDS_; int wd = j - se * WORDS_;
                val = qa_word_bank[((wd * B_ + b) * SENTS_ + se) * D_ + d0 + tx];
            }
            tile[ty + a * 8][tx] = val;
        }
        __syncthreads();
        ushort_t* base = mt + (size_t)b * D_ * NK_;
#pragma unroll
        for (int a = 0; a < 4; ++a) {
            int d = d0 + ty + a * 8;
            base[(size_t)d * NK_ + s0 + tx] = f2b(tile[tx][ty + a * 8]);
        }
    }
}

// ---------------- k1: all projections via bf16 MFMA, fp32*C2L2E out to ws ----------------
// Compact 1D grid (624 blocks): z0-2: 32 blocks each (M=200), z3: 320 (M=2560),
// z4: 200 (M=1600), z5: 8 (M=64). Block tile 64x64, K=512 in 16 steps.
// Depth-2 register prefetch: A and Wt loads issued 2 steps ahead.
__global__ __launch_bounds__(256) void k1_gemm(
    const float* __restrict__ source, const float* __restrict__ src_bank,
    const float* __restrict__ qa_sent_bank, const float* __restrict__ qa_word_bank,
    const ushort_t* __restrict__ wt,
    const float* __restrict__ bq_word, const float* __restrict__ bq_sent,
    const float* __restrict__ bq_pass,
    float* __restrict__ wsf)
{
    __shared__ short At[64 * 32];
    __shared__ short Bt[64 * 32];
    int bid = blockIdx.x;
    int z, rem;
    if (bid < 96)       { z = bid >> 5; rem = bid & 31; }
    else if (bid < 416) { z = 3; rem = bid - 96; }
    else if (bid < 616) { z = 4; rem = bid - 416; }
    else                { z = 5; rem = bid - 616; }
    int by = rem >> 3, bx = rem & 7;
    int M, atype; const float* bias; float* C;
    switch (z) {
        case 0: M = 200;  atype = 0; bias = bq_word; C = wsf + OFF_WQ_WORD; break;
        case 1: M = 200;  atype = 0; bias = bq_sent; C = wsf + OFF_WQ_SENT; break;
        case 2: M = 200;  atype = 0; bias = bq_pass; C = wsf + OFF_WQ_PASS; break;
        case 3: M = 2560; atype = 1; bias = nullptr; C = wsf + OFF_UH_WORD; break;
        case 4: M = 1600; atype = 2; bias = nullptr; C = wsf + OFF_UH_SRC;  break;
        default: M = 64;  atype = 3; bias = nullptr; C = wsf + OFF_UH_SENT; break;
    }
    int m0 = by * 64, n0 = bx * 64;
    const ushort_t* W = wt + z * (D_ * D_);   // Wt: [n][k] bf16

    int tid = threadIdx.x;
    int lane = tid & 63, wv = tid >> 6;
    int quad = lane >> 4, l16 = lane & 15;
    int sm = tid >> 2, koff = (tid & 3) * 8;  // staging: row sm, 8-elem chunk koff

    // A-row gather base (row -> global f32 pointer per segment type)
    const float* arow = nullptr;
    {
        int r = m0 + sm;
        if (r < M) {
            if (atype == 0) arow = source + r * D_;
            else if (atype == 1) { int b = r / NW_; int j = r - b * NW_;
                                   int se = j / WORDS_; int wd = j - se * WORDS_;
                                   arow = qa_word_bank + ((wd * B_ + b) * SENTS_ + se) * D_; }
            else if (atype == 2) { int b = r / SRC_; int j = r - b * SRC_;
                                   arow = src_bank + (j * B_ + b) * D_; }
            else                 { int b = r >> 4; int s2 = r & 15;
                                   arow = qa_sent_bank + (s2 * B_ + b) * D_; }
        }
    }
    const ushort_t* wrow = W + (n0 + sm) * D_;

    auto loadA = [&](float* r, int kk) {
        if (arow) {
            float4 f0 = *(const float4*)(arow + kk * 32 + koff);
            float4 f1 = *(const float4*)(arow + kk * 32 + koff + 4);
            r[0]=f0.x; r[1]=f0.y; r[2]=f0.z; r[3]=f0.w;
            r[4]=f1.x; r[5]=f1.y; r[6]=f1.z; r[7]=f1.w;
        } else {
#pragma unroll
            for (int i = 0; i < 8; ++i) r[i] = 0.f;
        }
    };

    f4v acc[4] = { {0.f,0.f,0.f,0.f}, {0.f,0.f,0.f,0.f},
                   {0.f,0.f,0.f,0.f}, {0.f,0.f,0.f,0.f} };

    // depth-2 prefetch pipeline
    float a0[8], a1[8];
    int4 w0v, w1v;
    loadA(a0, 0); w0v = *(const int4*)(wrow + 0 * 32 + koff);
    loadA(a1, 1); w1v = *(const int4*)(wrow + 1 * 32 + koff);

    for (int kk = 0; kk < 16; ++kk) {
        // store current tiles to LDS
        union { ushort_t u[8]; int4 v; } pk;
#pragma unroll
        for (int i = 0; i < 8; ++i) pk.u[i] = f2b(a0[i]);
        *(int4*)(At + sm * 32 + koff) = pk.v;
        *(int4*)(Bt + sm * 32 + koff) = w0v;
        __syncthreads();
        // rotate + prefetch kk+2 (lands by the time it is stored, ~2 iters later)
#pragma unroll
        for (int i = 0; i < 8; ++i) a0[i] = a1[i];
        w0v = w1v;
        if (kk < 14) {
            loadA(a1, kk + 2);
            w1v = *(const int4*)(wrow + (kk + 2) * 32 + koff);
        }
        s8v af = *(const s8v*)(At + (wv * 16 + l16) * 32 + quad * 8);
#pragma unroll
        for (int ng = 0; ng < 4; ++ng) {
            s8v bf = *(const s8v*)(Bt + (ng * 16 + l16) * 32 + quad * 8);
            acc[ng] = __builtin_amdgcn_mfma_f32_16x16x32_bf16(af, bf, acc[ng], 0, 0, 0);
        }
        __syncthreads();
    }
    // epilogue: D col = lane&15, row = quad*4 + r. Pre-scale by 2*log2e so
    // k2 can use exp2 directly: stored value = (acc+bias) * C2L2E.
#pragma unroll
    for (int ng = 0; ng < 4; ++ng) {
        int col = n0 + ng * 16 + l16;
        float bb = bias ? bias[col] : 0.f;
#pragma unroll
        for (int rr = 0; rr < 4; ++rr) {
            int row = m0 + wv * 16 + quad * 4 + rr;
            if (row < M) C[row * D_ + col] = (acc[ng][rr] + bb) * C2L2E;
        }
    }
}

// ---------------- k2: additive-attention scores — 5 wave-fifths per job ----------------
// 5280 blocks x 4 waves = 21120 wave-fifths: (b, slot, fifth-of-t). Each active
// wave computes 10 t-rows for one slot (2 groups of 5 statically-indexed
// accumulators — no local-memory scratch). Masked jobs exit immediately.
// score = Vsum - 2*sum_d v[d]*sigmoid(-2x); exp(2x)=exp2(pre-scaled sum).
__global__ __launch_bounds__(256) void k2_scores(
    const float* __restrict__ v_word, const float* __restrict__ v_sent,
    const float* __restrict__ v_pass,
    const int* __restrict__ src_lengths, const int* __restrict__ qa_word_lengths,
    float* __restrict__ wsf)
{
    int lane = threadIdx.x & 63;
    int jid = blockIdx.x * 4 + (threadIdx.x >> 6);   // 21120 wave-fifths, exact
    int job = jid / 5, fifth = jid - job * 5;
    int b = job / NJOB_, slot = job - b * NJOB_;
    const float* uh; const float* v; const float* wq; float* out; int ostride;
    if (slot < SRC_) {
        if (slot >= src_lengths[b]) return;           // masked: value never read
        uh = wsf + OFF_UH_SRC + (size_t)(b * SRC_ + slot) * D_;
        v = v_pass; wq = wsf + OFF_WQ_PASS + b * T_ * D_;
        out = wsf + OFF_SC_SRC + b * T_ * SRC_ + slot; ostride = SRC_;
    } else if (slot < NMEM_) {
        int j = slot - SRC_;
        int se = j / WORDS_; int wd = j - se * WORDS_;
        if (wd >= qa_word_lengths[b * SENTS_ + se]) return;  // masked
        uh = wsf + OFF_UH_WORD + (size_t)(b * NW_ + j) * D_;
        v = v_word; wq = wsf + OFF_WQ_WORD + b * T_ * D_;
        out = wsf + OFF_SC_WORD + b * T_ * NW_ + j; ostride = NW_;
    } else {
        int s2 = slot - NMEM_;
        uh = wsf + OFF_UH_SENT + (size_t)(b * SENTS_ + s2) * D_;
        v = v_sent; wq = wsf + OFF_WQ_SENT + b * T_ * D_;
        out = wsf + OFF_SC_SENT + b * T_ * SENTS_ + s2; ostride = SENTS_;
    }
    int d0 = lane * 8;
    float4 u0 = *(const float4*)(uh + d0);
    float4 u1 = *(const float4*)(uh + d0 + 4);
    float uhr[8] = {u0.x, u0.y, u0.z, u0.w, u1.x, u1.y, u1.z, u1.w};
    float4 v0 = *(const float4*)(v + d0);
    float4 v1 = *(const float4*)(v + d0 + 4);
    float vr[8] = {v0.x, v0.y, v0.z, v0.w, v1.x, v1.y, v1.z, v1.w};

    // Vsum = sum_d v[d] (broadcast to all lanes)
    float vs = ((vr[0] + vr[1]) + (vr[2] + vr[3])) + ((vr[4] + vr[5]) + (vr[6] + vr[7]));
#pragma unroll
    for (int off = 32; off > 0; off >>= 1) vs += __shfl_xor(vs, off, 64);

    const float* wqh = wq + (fifth * 10) * D_ + d0;
    int tbase = fifth * 10;
#pragma unroll 1
    for (int g = 0; g < 2; ++g) {
        float a5[5];
#pragma unroll
        for (int u5 = 0; u5 < 5; ++u5) {
            const float* wr = wqh + (g * 5 + u5) * D_;
            float4 w0 = *(const float4*)(wr);
            float4 w1 = *(const float4*)(wr + 4);
            float wrr[8] = {w0.x, w0.y, w0.z, w0.w, w1.x, w1.y, w1.z, w1.w};
            float a = 0.f;
#pragma unroll
            for (int j = 0; j < 8; ++j) {
                float e = __builtin_amdgcn_exp2f(wrr[j] + uhr[j]);  // exp(2x)
                float r = __builtin_amdgcn_rcpf(e + 1.f);           // sigmoid(-2x)
                a = fmaf(vr[j], r, a);
            }
            a5[u5] = a;
        }
        // 5 interleaved butterfly reductions (all indices static -> registers)
#pragma unroll
        for (int off = 32; off > 0; off >>= 1) {
#pragma unroll
            for (int u5 = 0; u5 < 5; ++u5) a5[u5] += __shfl_xor(a5[u5], off, 64);
        }
        if (lane == 0) {
#pragma unroll
            for (int u5 = 0; u5 < 5; ++u5)
                out[(tbase + g * 5 + u5) * ostride] = fmaf(-2.f, a5[u5], vs);
        }
    }
}

// ---------------- k3a: hier combine + mask + softmax -> bf16 P[b][64][1056] ----------------
__global__ __launch_bounds__(256) void k3a_softmax(
    const int* __restrict__ src_lengths, const int* __restrict__ qa_word_lengths,
    const float* __restrict__ wsf, ushort_t* __restrict__ P)
{
    __shared__ float p[NMEM_];
    __shared__ float red[4];
    int tid = threadIdx.x, lane = tid & 63, wv = tid >> 6;
    int bt = blockIdx.x, b = bt / T_, t = bt - b * T_;
    const float* sc_src  = wsf + OFF_SC_SRC  + bt * SRC_;
    const float* sc_word = wsf + OFF_SC_WORD + bt * NW_;
    const float* sc_sent = wsf + OFF_SC_SENT + bt * SENTS_;
    int slen = src_lengths[b];
    float mx = -3.0e38f;
    for (int j = tid; j < NMEM_; j += 256) {
        float val;
        if (j < SRC_) {
            val = (j < slen) ? sc_src[j] : -1e30f;
        } else {
            int jj = j - SRC_; int se = jj / WORDS_; int wd = jj - se * WORDS_;
            float raw = sc_word[jj] * sc_sent[se];
            val = (wd < qa_word_lengths[b * SENTS_ + se]) ? raw : -1e30f;
        }
        p[j] = val;
        mx = fmaxf(mx, val);
    }
#pragma unroll
    for (int off = 32; off > 0; off >>= 1) mx = fmaxf(mx, __shfl_xor(mx, off, 64));
    if (lane == 0) red[wv] = mx;
    __syncthreads();
    mx = fmaxf(fmaxf(red[0], red[1]), fmaxf(red[2], red[3]));
    __syncthreads();
    float lsum = 0.f;
    for (int j = tid; j < NMEM_; j += 256) {
        float e = __expf(p[j] - mx);
        p[j] = e; lsum += e;
    }
#pragma unroll
    for (int off = 32; off > 0; off >>= 1) lsum += __shfl_xor(lsum, off, 64);
    if (lane == 0) red[wv] = lsum;
    __syncthreads();
    float inv = 1.f / (red[0] + red[1] + red[2] + red[3]);
    ushort_t* prow = P + (size_t)(b * 64 + t) * NK_;
    for (int j = tid; j < NK_; j += 256)
        prow[j] = (j < NMEM_) ? f2b(p[j] * inv) : (ushort_t)0;
}

// ---------------- k3c: context GEMM  C[b][t][d] = sum_s P[t,s] * Mt[d,s] ----------------
// grid (16 d-tiles, 4 b), 256 thr. Tile 64(t,pad) x 32(d), K=1056.
// Depth-3 register prefetch of P (int4) and Mt (int2).
__global__ __launch_bounds__(256) void k3c_gemm(
    const ushort_t* __restrict__ P, const ushort_t* __restrict__ Mt,
    float* __restrict__ out)
{
    __shared__ short At[64 * 32];
    __shared__ short Bt[32 * 32];
    int b = blockIdx.y;
    int n0 = blockIdx.x * 32;
    int tid = threadIdx.x;
    int lane = tid & 63, wv = tid >> 6;
    int quad = lane >> 4, l16 = lane & 15;
    int smA = tid >> 2, koffA = (tid & 3) * 8;   // A: 64 rows x 32k, int4/thread
    int smB = tid >> 3, koffB = (tid & 7) * 4;   // B: 32 rows x 32k, int2/thread

    const ushort_t* arow = P + (size_t)(b * 64 + smA) * NK_ + koffA;
    const ushort_t* brow = Mt + ((size_t)(b * D_ + n0 + smB)) * NK_ + koffB;

    f4v acc[2] = { {0.f,0.f,0.f,0.f}, {0.f,0.f,0.f,0.f} };

    // depth-3 prefetch pipeline (invariant entering kk: a0=k(kk), a1=k(kk+1), a2=k(kk+2))
    int4 a0 = *(const int4*)(arow);
    int2 b0 = *(const int2*)(brow);
    int4 a1 = *(const int4*)(arow + 32);
    int2 b1 = *(const int2*)(brow + 32);
    int4 a2 = *(const int4*)(arow + 64);
    int2 b2 = *(const int2*)(brow + 64);

    for (int kk = 0; kk < 33; ++kk) {
        *(int4*)(At + smA * 32 + koffA) = a0;
        *(int2*)(Bt + smB * 32 + koffB) = b0;
        __syncthreads();
        a0 = a1; a1 = a2; b0 = b1; b1 = b2;
        if (kk < 30) {
            a2 = *(const int4*)(arow + (kk + 3) * 32);
            b2 = *(const int2*)(brow + (kk + 3) * 32);
        }
        s8v af = *(const s8v*)(At + (wv * 16 + l16) * 32 + quad * 8);
#pragma unroll
        for (int ng = 0; ng < 2; ++ng) {
            s8v bf = *(const s8v*)(Bt + (ng * 16 + l16) * 32 + quad * 8);
            acc[ng] = __builtin_amdgcn_mfma_f32_16x16x32_bf16(af, bf, acc[ng], 0, 0, 0);
        }
        __syncthreads();
    }
#pragma unroll
    for (int ng = 0; ng < 2; ++ng) {
        int col = n0 + ng * 16 + l16;
#pragma unroll
        for (int rr = 0; rr < 4; ++rr) {
            int row = wv * 16 + quad * 4 + rr;   // t
            if (row < T_) out[(size_t)(b * T_ + row) * D_ + col] = acc[ng][rr];
        }
    }
}

extern "C" void kernel_launch(void* const* d_in, const int* in_sizes, int n_in,
                              void* d_out, int out_size, void* d_ws, size_t ws_size,
                              hipStream_t stream)
{
    (void)in_sizes; (void)n_in; (void)out_size; (void)ws_size;
    const float* source          = (const float*)d_in[0];
    const float* src_bank        = (const float*)d_in[1];
    const int*   src_lengths     = (const int*)d_in[2];
    const float* qa_sent_bank    = (const float*)d_in[3];
    /* d_in[4] qa_sent_lengths unused (matches reference) */
    const float* qa_word_bank    = (const float*)d_in[5];
    const int*   qa_word_lengths = (const int*)d_in[6];
    const float* Wq_word = (const float*)d_in[7];
    const float* bq_word = (const float*)d_in[8];
    const float* Uc_word = (const float*)d_in[9];
    const float* v_word  = (const float*)d_in[10];
    const float* Wq_sent = (const float*)d_in[11];
    const float* bq_sent = (const float*)d_in[12];
    const float* Uc_sent = (const float*)d_in[13];
    const float* v_sent  = (const float*)d_in[14];
    const float* Wq_pass = (const float*)d_in[15];
    const float* bq_pass = (const float*)d_in[16];
    const float* Uc_pass = (const float*)d_in[17];
    const float* v_pass  = (const float*)d_in[18];

    float* wsf = (float*)d_ws;
    ushort_t* Pb  = (ushort_t*)((char*)d_ws + P_BYTE_OFF);
    ushort_t* mt  = (ushort_t*)((char*)d_ws + MT_BYTE_OFF);
    ushort_t* wt  = (ushort_t*)((char*)d_ws + WT_BYTE_OFF);
    float* out = (float*)d_out;

    // Wt slot order must match k1 segment order:
    // 0:Wq_word 1:Wq_sent 2:Wq_pass 3:Uc_word 4:Uc_pass 5:Uc_sent
    k0f_transpose<<<dim3(3648), dim3(256), 0, stream>>>(
        Wq_word, Wq_sent, Wq_pass, Uc_word, Uc_pass, Uc_sent,
        src_bank, qa_word_bank, wt, mt);
    k1_gemm<<<dim3(624), dim3(256), 0, stream>>>(
        source, src_bank, qa_sent_bank, qa_word_bank, wt,
        bq_word, bq_sent, bq_pass, wsf);
    k2_scores<<<dim3(5280), dim3(256), 0, stream>>>(
        v_word, v_sent, v_pass, src_lengths, qa_word_lengths, wsf);
    k3a_softmax<<<dim3(200), dim3(256), 0, stream>>>(src_lengths, qa_word_lengths, wsf, Pb);
    k3c_gemm<<<dim3(16, 4), dim3(256), 0, stream>>>(Pb, mt, out);
}